// Round 1
// baseline (259.998 us; speedup 1.0000x reference)
//
#include <hip/hip_runtime.h>
#include <hip/hip_bf16.h>
#include <math.h>

#define S_LEN 2048
#define NHEAD 16
#define DHEAD 128

typedef __attribute__((ext_vector_type(8))) _Float16 f16x8;
typedef __attribute__((ext_vector_type(4))) _Float16 f16x4;
typedef __attribute__((ext_vector_type(4))) float f32x4;

// ---------------------------------------------------------------------------
// Kernel 1: transpose the two SVD weight mats [H][d][e] f32 -> [H][e][d] f16
// so the projection's MFMA B-fragments become contiguous 16B loads.
// ---------------------------------------------------------------------------
__global__ __launch_bounds__(256) void transpose_w_kernel(
    const float* __restrict__ w_qk, const float* __restrict__ w_v,
    _Float16* __restrict__ wqk_t, _Float16* __restrict__ wv_t)
{
    __shared__ float tile[32][33];
    const int mat = blockIdx.z;          // 0 = qk, 1 = v
    const int h   = blockIdx.y;
    const int t0  = blockIdx.x;          // 16 tiles of 32x32
    const int dt  = (t0 >> 2) * 32;
    const int et  = (t0 & 3) * 32;
    const float* src = (mat ? w_v : w_qk) + (size_t)h * DHEAD * DHEAD;
    _Float16*   dst = (mat ? wv_t : wqk_t) + (size_t)h * DHEAD * DHEAD;
    const int tx = threadIdx.x & 31, ty = threadIdx.x >> 5;   // 32 x 8
#pragma unroll
    for (int k = 0; k < 4; ++k)
        tile[ty + 8 * k][tx] = src[(size_t)(dt + ty + 8 * k) * DHEAD + et + tx];
    __syncthreads();
#pragma unroll
    for (int k = 0; k < 4; ++k)
        dst[(size_t)(et + ty + 8 * k) * DHEAD + dt + tx] = (_Float16)tile[tx][ty + 8 * k];
}

// ---------------------------------------------------------------------------
// Kernel 2: per-head projection via MFMA 16x16x32 f16.
//   Qp[h][s][e] = (X_q[s] @ W_qk) / sqrt(128)   (f16)
//   Kp[h][s][e] =  X_k[s] @ W_qk                (f16)
//   Vt[h][e][s] =  X_v[s] @ W_v (transposed)    (f16)
// Block: 256 thr (4 waves), each block = one head x 64 rows.
// ---------------------------------------------------------------------------
__global__ __launch_bounds__(256) void proj_kernel(
    const float* __restrict__ q_in, const float* __restrict__ k_in,
    const float* __restrict__ v_in,
    const _Float16* __restrict__ wqk_t, const _Float16* __restrict__ wv_t,
    _Float16* __restrict__ Qp, _Float16* __restrict__ Kp, _Float16* __restrict__ Vt)
{
    const int h   = blockIdx.x >> 5;
    const int rb  = blockIdx.x & 31;
    const int wv  = threadIdx.x >> 6;
    const int lane = threadIdx.x & 63;
    const int r16 = lane & 15;
    const int kg  = lane >> 4;
    const int s_base = rb * 64 + wv * 16;
    const int s_row  = s_base + r16;
    const float INV_NORM = 0.08838834764831845f;   // 1/sqrt(128)

    // A-fragments for the wave's 16 rows: lane holds X[row=r16][kb*32+kg*8 + i]
    f16x8 aq[4], ak[4], av[4];
    {
        const float* qr = q_in + ((size_t)s_row * NHEAD + h) * DHEAD;
        const float* kr = k_in + ((size_t)s_row * NHEAD + h) * DHEAD;
        const float* vr = v_in + ((size_t)s_row * NHEAD + h) * DHEAD;
#pragma unroll
        for (int kb = 0; kb < 4; ++kb) {
            const int d0 = kb * 32 + kg * 8;
            const f32x4 q0 = *(const f32x4*)(qr + d0), q1 = *(const f32x4*)(qr + d0 + 4);
            const f32x4 k0 = *(const f32x4*)(kr + d0), k1 = *(const f32x4*)(kr + d0 + 4);
            const f32x4 v0 = *(const f32x4*)(vr + d0), v1 = *(const f32x4*)(vr + d0 + 4);
#pragma unroll
            for (int i = 0; i < 4; ++i) {
                aq[kb][i] = (_Float16)q0[i];  aq[kb][i + 4] = (_Float16)q1[i];
                ak[kb][i] = (_Float16)k0[i];  ak[kb][i + 4] = (_Float16)k1[i];
                av[kb][i] = (_Float16)v0[i];  av[kb][i + 4] = (_Float16)v1[i];
            }
        }
    }

    const _Float16* wq_h = wqk_t + (size_t)h * DHEAD * DHEAD;
    const _Float16* wv_h = wv_t  + (size_t)h * DHEAD * DHEAD;

#pragma unroll 2
    for (int cb = 0; cb < 8; ++cb) {
        f32x4 accq = {0.f, 0.f, 0.f, 0.f};
        f32x4 acck = {0.f, 0.f, 0.f, 0.f};
        f32x4 accv = {0.f, 0.f, 0.f, 0.f};
        const int c = cb * 16 + r16;
#pragma unroll
        for (int kb = 0; kb < 4; ++kb) {
            // B-fragment: lane holds W[k = kb*32+kg*8 + i][col = c] = Wt[c][k...]
            const f16x8 bqk = *(const f16x8*)(wq_h + (size_t)c * DHEAD + kb * 32 + kg * 8);
            const f16x8 bv  = *(const f16x8*)(wv_h + (size_t)c * DHEAD + kb * 32 + kg * 8);
            accq = __builtin_amdgcn_mfma_f32_16x16x32_f16(aq[kb], bqk, accq, 0, 0, 0);
            acck = __builtin_amdgcn_mfma_f32_16x16x32_f16(ak[kb], bqk, acck, 0, 0, 0);
            accv = __builtin_amdgcn_mfma_f32_16x16x32_f16(av[kb], bv,  accv, 0, 0, 0);
        }
        // C/D layout: row = kg*4 + j, col = r16
#pragma unroll
        for (int j = 0; j < 4; ++j) {
            const int sr = s_base + kg * 4 + j;
            Qp[((size_t)h * S_LEN + sr) * DHEAD + c] = (_Float16)(accq[j] * INV_NORM);
            Kp[((size_t)h * S_LEN + sr) * DHEAD + c] = (_Float16)acck[j];
        }
        f16x4 vvv;
#pragma unroll
        for (int j = 0; j < 4; ++j) vvv[j] = (_Float16)accv[j];
        *(f16x4*)(Vt + ((size_t)h * DHEAD + c) * S_LEN + s_base + kg * 4) = vvv;
    }
}

// ---------------------------------------------------------------------------
// Kernel 3: causal flash attention.
// Grid (S/64, H); block 256 thr = 4 waves, wave w owns q-rows [q0+16w, +16).
// KV tiles of 32. Online softmax; P goes through wave-private LDS to reach
// the PV A-fragment layout.
// ---------------------------------------------------------------------------
__global__ __launch_bounds__(256) void attn_kernel(
    const _Float16* __restrict__ Qp, const _Float16* __restrict__ Kp,
    const _Float16* __restrict__ Vt, float* __restrict__ out)
{
    __shared__ _Float16 ps[4][16][32];
    const int h  = blockIdx.y;
    const int q0 = blockIdx.x * 64;
    const int wv = threadIdx.x >> 6;
    const int lane = threadIdx.x & 63;
    const int r16 = lane & 15;
    const int kg  = lane >> 4;

    const int qrow = q0 + wv * 16 + r16;
    f16x8 qf[4];
    {
        const _Float16* qp = Qp + ((size_t)h * S_LEN + qrow) * DHEAD;
#pragma unroll
        for (int kb = 0; kb < 4; ++kb)
            qf[kb] = *(const f16x8*)(qp + kb * 32 + kg * 8);
    }

    f32x4 acc_o[8];
#pragma unroll
    for (int d0 = 0; d0 < 8; ++d0) acc_o[d0] = (f32x4){0.f, 0.f, 0.f, 0.f};
    float m_run[4], l_run[4];
#pragma unroll
    for (int j = 0; j < 4; ++j) { m_run[j] = -INFINITY; l_run[j] = 0.f; }

    const _Float16* kbase = Kp + (size_t)h * S_LEN * DHEAD;
    const _Float16* vbase = Vt + (size_t)h * DHEAD * S_LEN;
    const int kv_end = q0 + 64;

    for (int kv0 = 0; kv0 < kv_end; kv0 += 32) {
        // --- S = Q K^T (pre-scaled Q) ---
        f32x4 sacc[2];
        sacc[0] = (f32x4){0.f, 0.f, 0.f, 0.f};
        sacc[1] = (f32x4){0.f, 0.f, 0.f, 0.f};
#pragma unroll
        for (int ckv = 0; ckv < 2; ++ckv) {
            const _Float16* kp = kbase + (size_t)(kv0 + ckv * 16 + r16) * DHEAD + kg * 8;
#pragma unroll
            for (int kb = 0; kb < 4; ++kb) {
                const f16x8 kf = *(const f16x8*)(kp + kb * 32);
                sacc[ckv] = __builtin_amdgcn_mfma_f32_16x16x32_f16(qf[kb], kf, sacc[ckv], 0, 0, 0);
            }
        }
        // --- causal mask ---
#pragma unroll
        for (int ckv = 0; ckv < 2; ++ckv) {
            const int k_abs = kv0 + ckv * 16 + r16;
#pragma unroll
            for (int j = 0; j < 4; ++j) {
                const int q_abs = q0 + wv * 16 + kg * 4 + j;
                if (k_abs > q_abs) sacc[ckv][j] = -1e30f;
            }
        }
        // --- online softmax ---
        float mt[4];
#pragma unroll
        for (int j = 0; j < 4; ++j) mt[j] = fmaxf(sacc[0][j], sacc[1][j]);
#pragma unroll
        for (int xm = 1; xm < 16; xm <<= 1)
#pragma unroll
            for (int j = 0; j < 4; ++j)
                mt[j] = fmaxf(mt[j], __shfl_xor(mt[j], xm, 64));
        float corr[4], rs[4];
#pragma unroll
        for (int j = 0; j < 4; ++j) {
            const float mn = fmaxf(m_run[j], mt[j]);
            corr[j] = __expf(m_run[j] - mn);
            m_run[j] = mn;
            rs[j] = 0.f;
        }
#pragma unroll
        for (int ckv = 0; ckv < 2; ++ckv)
#pragma unroll
            for (int j = 0; j < 4; ++j) {
                const float p = __expf(sacc[ckv][j] - m_run[j]);
                sacc[ckv][j] = p;
                rs[j] += p;
            }
#pragma unroll
        for (int xm = 1; xm < 16; xm <<= 1)
#pragma unroll
            for (int j = 0; j < 4; ++j)
                rs[j] += __shfl_xor(rs[j], xm, 64);
#pragma unroll
        for (int j = 0; j < 4; ++j)
            l_run[j] = l_run[j] * corr[j] + rs[j];
#pragma unroll
        for (int d0 = 0; d0 < 8; ++d0)
#pragma unroll
            for (int j = 0; j < 4; ++j)
                acc_o[d0][j] *= corr[j];

        // --- P (C/D layout) -> LDS -> A-fragment layout ---
#pragma unroll
        for (int ckv = 0; ckv < 2; ++ckv)
#pragma unroll
            for (int j = 0; j < 4; ++j)
                ps[wv][kg * 4 + j][ckv * 16 + r16] = (_Float16)sacc[ckv][j];
        asm volatile("s_waitcnt lgkmcnt(0)" ::: "memory");
        __builtin_amdgcn_sched_barrier(0);
        const f16x8 pf = *(const f16x8*)&ps[wv][r16][kg * 8];

        // --- O += P V ---
#pragma unroll
        for (int d0 = 0; d0 < 8; ++d0) {
            const f16x8 vf = *(const f16x8*)(vbase + (size_t)(d0 * 16 + r16) * S_LEN + kv0 + kg * 8);
            acc_o[d0] = __builtin_amdgcn_mfma_f32_16x16x32_f16(pf, vf, acc_o[d0], 0, 0, 0);
        }
    }

    // --- epilogue: normalize, write ctx[q][h][e] f32 ---
#pragma unroll
    for (int d0 = 0; d0 < 8; ++d0) {
#pragma unroll
        for (int j = 0; j < 4; ++j) {
            const int qr = q0 + wv * 16 + kg * 4 + j;
            out[(size_t)qr * (NHEAD * DHEAD) + h * DHEAD + d0 * 16 + r16] =
                acc_o[d0][j] / l_run[j];
        }
    }
}

// ---------------------------------------------------------------------------
extern "C" void kernel_launch(void* const* d_in, const int* in_sizes, int n_in,
                              void* d_out, int out_size, void* d_ws, size_t ws_size,
                              hipStream_t stream) {
    const float* q_in = (const float*)d_in[0];
    const float* k_in = (const float*)d_in[1];
    const float* v_in = (const float*)d_in[2];
    // d_in[3] = attention_mask (strict causal triu) -- implemented analytically
    const float* w_qk = (const float*)d_in[4];
    const float* w_v  = (const float*)d_in[5];
    float* out = (float*)d_out;

    const size_t mat_elems = (size_t)NHEAD * S_LEN * DHEAD;   // 4 Mi
    const size_t w_elems   = (size_t)NHEAD * DHEAD * DHEAD;   // 256 Ki
    _Float16* Qp   = (_Float16*)d_ws;
    _Float16* Kp   = Qp + mat_elems;
    _Float16* Vt   = Kp + mat_elems;
    _Float16* Wqkt = Vt + mat_elems;
    _Float16* Wvt  = Wqkt + w_elems;

    transpose_w_kernel<<<dim3(16, NHEAD, 2), dim3(256), 0, stream>>>(w_qk, w_v, Wqkt, Wvt);
    proj_kernel<<<dim3(NHEAD * 32), dim3(256), 0, stream>>>(q_in, k_in, v_in, Wqkt, Wvt, Qp, Kp, Vt);
    attn_kernel<<<dim3(S_LEN / 64, NHEAD), dim3(256), 0, stream>>>(Qp, Kp, Vt, out);
}

// Round 2
// 105.008 us; speedup vs baseline: 2.4760x; 2.4760x over previous
//
#include <hip/hip_runtime.h>
#include <hip/hip_bf16.h>
#include <math.h>

#define S_LEN 2048
#define NHEAD 16
#define DHEAD 128

typedef __attribute__((ext_vector_type(8)))  _Float16 f16x8;
typedef __attribute__((ext_vector_type(4)))  _Float16 f16x4;
typedef __attribute__((ext_vector_type(2)))  _Float16 f16x2;
typedef __attribute__((ext_vector_type(4)))  float    f32x4;
typedef __attribute__((ext_vector_type(16))) float    f32x16;

// v_permlane32_swap_b32: a' = {a.lo, b.lo}, b' = {a.hi, b.hi}
__device__ __forceinline__ void permswap(unsigned &a, unsigned &b) {
    asm volatile("v_permlane32_swap_b32 %0, %1" : "+v"(a), "+v"(b));
}

// ---------------------------------------------------------------------------
// Kernel 1: transpose the two SVD weight mats [H][d][e] f32 -> [H][e][d] f16
// ---------------------------------------------------------------------------
__global__ __launch_bounds__(256) void transpose_w_kernel(
    const float* __restrict__ w_qk, const float* __restrict__ w_v,
    _Float16* __restrict__ wqk_t, _Float16* __restrict__ wv_t)
{
    __shared__ float tile[32][33];
    const int mat = blockIdx.z;
    const int h   = blockIdx.y;
    const int t0  = blockIdx.x;
    const int dt  = (t0 >> 2) * 32;
    const int et  = (t0 & 3) * 32;
    const float* src = (mat ? w_v : w_qk) + (size_t)h * DHEAD * DHEAD;
    _Float16*   dst = (mat ? wv_t : wqk_t) + (size_t)h * DHEAD * DHEAD;
    const int tx = threadIdx.x & 31, ty = threadIdx.x >> 5;
#pragma unroll
    for (int k = 0; k < 4; ++k)
        tile[ty + 8 * k][tx] = src[(size_t)(dt + ty + 8 * k) * DHEAD + et + tx];
    __syncthreads();
#pragma unroll
    for (int k = 0; k < 4; ++k)
        dst[(size_t)(et + ty + 8 * k) * DHEAD + dt + tx] = (_Float16)tile[tx][ty + 8 * k];
}

// ---------------------------------------------------------------------------
// Kernel 2: per-head projection via MFMA 16x16x32 f16.
//   Qp[h][s][e] = (X_q[s] @ W_qk) / sqrt(128)   (f16, pre-scaled)
//   Kp[h][s][e] =  X_k[s] @ W_qk                (f16)
//   Vt[h][e][s] =  X_v[s] @ W_v (transposed)    (f16)
// ---------------------------------------------------------------------------
__global__ __launch_bounds__(256) void proj_kernel(
    const float* __restrict__ q_in, const float* __restrict__ k_in,
    const float* __restrict__ v_in,
    const _Float16* __restrict__ wqk_t, const _Float16* __restrict__ wv_t,
    _Float16* __restrict__ Qp, _Float16* __restrict__ Kp, _Float16* __restrict__ Vt)
{
    const int h   = blockIdx.x >> 5;
    const int rb  = blockIdx.x & 31;
    const int wv  = threadIdx.x >> 6;
    const int lane = threadIdx.x & 63;
    const int r16 = lane & 15;
    const int kg  = lane >> 4;
    const int s_base = rb * 64 + wv * 16;
    const int s_row  = s_base + r16;
    const float INV_NORM = 0.08838834764831845f;   // 1/sqrt(128)

    f16x8 aq[4], ak[4], av[4];
    {
        const float* qr = q_in + ((size_t)s_row * NHEAD + h) * DHEAD;
        const float* kr = k_in + ((size_t)s_row * NHEAD + h) * DHEAD;
        const float* vr = v_in + ((size_t)s_row * NHEAD + h) * DHEAD;
#pragma unroll
        for (int kb = 0; kb < 4; ++kb) {
            const int d0 = kb * 32 + kg * 8;
            const f32x4 q0 = *(const f32x4*)(qr + d0), q1 = *(const f32x4*)(qr + d0 + 4);
            const f32x4 k0 = *(const f32x4*)(kr + d0), k1 = *(const f32x4*)(kr + d0 + 4);
            const f32x4 v0 = *(const f32x4*)(vr + d0), v1 = *(const f32x4*)(vr + d0 + 4);
#pragma unroll
            for (int i = 0; i < 4; ++i) {
                aq[kb][i] = (_Float16)q0[i];  aq[kb][i + 4] = (_Float16)q1[i];
                ak[kb][i] = (_Float16)k0[i];  ak[kb][i + 4] = (_Float16)k1[i];
                av[kb][i] = (_Float16)v0[i];  av[kb][i + 4] = (_Float16)v1[i];
            }
        }
    }

    const _Float16* wq_h = wqk_t + (size_t)h * DHEAD * DHEAD;
    const _Float16* wv_h = wv_t  + (size_t)h * DHEAD * DHEAD;

#pragma unroll 2
    for (int cb = 0; cb < 8; ++cb) {
        f32x4 accq = {0.f, 0.f, 0.f, 0.f};
        f32x4 acck = {0.f, 0.f, 0.f, 0.f};
        f32x4 accv = {0.f, 0.f, 0.f, 0.f};
        const int c = cb * 16 + r16;
#pragma unroll
        for (int kb = 0; kb < 4; ++kb) {
            const f16x8 bqk = *(const f16x8*)(wq_h + (size_t)c * DHEAD + kb * 32 + kg * 8);
            const f16x8 bv  = *(const f16x8*)(wv_h + (size_t)c * DHEAD + kb * 32 + kg * 8);
            accq = __builtin_amdgcn_mfma_f32_16x16x32_f16(aq[kb], bqk, accq, 0, 0, 0);
            acck = __builtin_amdgcn_mfma_f32_16x16x32_f16(ak[kb], bqk, acck, 0, 0, 0);
            accv = __builtin_amdgcn_mfma_f32_16x16x32_f16(av[kb], bv,  accv, 0, 0, 0);
        }
#pragma unroll
        for (int j = 0; j < 4; ++j) {
            const int sr = s_base + kg * 4 + j;
            Qp[((size_t)h * S_LEN + sr) * DHEAD + c] = (_Float16)(accq[j] * INV_NORM);
            Kp[((size_t)h * S_LEN + sr) * DHEAD + c] = (_Float16)acck[j];
        }
        f16x4 vvv;
#pragma unroll
        for (int j = 0; j < 4; ++j) vvv[j] = (_Float16)accv[j];
        *(f16x4*)(Vt + ((size_t)h * DHEAD + c) * S_LEN + s_base + kg * 4) = vvv;
    }
}

// ---------------------------------------------------------------------------
// Kernel 3: causal flash attention, swapped-operand 32x32x16 MFMA,
// in-register softmax, KV-split with LDS combine, balanced q-tile pairing.
//
// Grid (16, H); block 512 thr = 8 waves:
//   wave w: qsub = w&1, role = (w>>1)&1 (A=even KV tiles, B=odd), tsel = w>>2
//   q-tile t = tsel ? 31-x : x  (64 rows), wave owns rows [64t+32*qsub, +32)
// Each SIMD hosts one light-tile and one heavy-tile wave -> balanced (33 tiles).
// S^T = K·Q^T: lane holds 16 scores of ONE q-row (q = lane&31).
// P^T redistribution for PV via cvt_pkrtz + v_permlane32_swap_b32 (no LDS).
// O^T = V^T·P^T; A/B partials merged through LDS at the end.
// ---------------------------------------------------------------------------
__global__ __launch_bounds__(512, 2) void attn_kernel(
    const _Float16* __restrict__ Qp, const _Float16* __restrict__ Kp,
    const _Float16* __restrict__ Vt, float* __restrict__ out)
{
    __shared__ _Float16 obuf[4][32][132];
    __shared__ float    mlbuf[4][2][32];

    const int h    = blockIdx.y;
    const int w    = threadIdx.x >> 6;
    const int lane = threadIdx.x & 63;
    const int q    = lane & 31;
    const int hi   = lane >> 5;

    const int qsub = w & 1;
    const int role = (w >> 1) & 1;
    const int tsel = w >> 2;
    const int t    = tsel ? (31 - blockIdx.x) : blockIdx.x;
    const int pairid = qsub + tsel * 2;
    const int q0w  = t * 64 + qsub * 32;
    const int jmax = 2 * t + 1 + qsub;
    const int q_abs = q0w + q;

    const _Float16* qbase = Qp + ((size_t)h * S_LEN + q0w) * DHEAD;
    const _Float16* kbase = Kp + (size_t)h * S_LEN * DHEAD;
    const _Float16* vbase = Vt + (size_t)h * DHEAD * S_LEN;

    const int lqk = q * DHEAD + hi * 8;   // lane offset in row-major [s][d]
    const int lv  = q * S_LEN + hi * 8;   // lane offset in [e][s]

    // Q fragments (B-operand): lane holds Q[q][16m + hi*8 + i]
    f16x8 qf[8];
#pragma unroll
    for (int m = 0; m < 8; ++m)
        qf[m] = *(const f16x8*)(qbase + lqk + m * 16);

    // O^T accumulators: acc[eb] covers e = eb*32 + (i&3)+8*(i>>2)+4*hi, col q
    f32x16 acc[4];
#pragma unroll
    for (int e = 0; e < 4; ++e)
#pragma unroll
        for (int i = 0; i < 16; ++i) acc[e][i] = 0.f;

    float m_run = -1e30f, l_run = 0.f;

    for (int j = role; j < jmax; j += 2) {
        const int kv0 = j * 32;

        // --- K fragments (A-operand): lane holds K[kv0+q][16m + hi*8 + i]
        const _Float16* kp = kbase + (size_t)kv0 * DHEAD + lqk;
        f16x8 kf[8];
#pragma unroll
        for (int m = 0; m < 8; ++m)
            kf[m] = *(const f16x8*)(kp + m * 16);

        // --- S^T = K · Q^T  (two chains to halve MFMA dep depth)
        f32x16 s0, s1;
#pragma unroll
        for (int i = 0; i < 16; ++i) { s0[i] = 0.f; s1[i] = 0.f; }
#pragma unroll
        for (int m = 0; m < 8; m += 2) {
            s0 = __builtin_amdgcn_mfma_f32_32x32x16_f16(kf[m],     qf[m],     s0, 0, 0, 0);
            s1 = __builtin_amdgcn_mfma_f32_32x32x16_f16(kf[m + 1], qf[m + 1], s1, 0, 0, 0);
        }

        // --- V fragments (issued here so latency hides under softmax)
        f16x8 vf[8];
#pragma unroll
        for (int e = 0; e < 4; ++e) {
            const _Float16* vp = vbase + (size_t)e * 32 * S_LEN + lv + kv0;
            vf[2 * e]     = *(const f16x8*)(vp);
            vf[2 * e + 1] = *(const f16x8*)(vp + 16);
        }

        f32x16 sv = s0 + s1;

        // --- causal mask (diagonal tile only)
        if (kv0 == q0w) {
#pragma unroll
            for (int i = 0; i < 16; ++i) {
                const int krel = (i & 3) + 8 * (i >> 2) + 4 * hi;
                if (kv0 + krel > q_abs) sv[i] = -1e30f;
            }
        }

        // --- in-register online softmax (per-lane = one q-row)
        float t0 = fmaxf(sv[0], sv[1]),  t1 = fmaxf(sv[2], sv[3]);
        float t2 = fmaxf(sv[4], sv[5]),  t3 = fmaxf(sv[6], sv[7]);
        float t4 = fmaxf(sv[8], sv[9]),  t5 = fmaxf(sv[10], sv[11]);
        float t6 = fmaxf(sv[12], sv[13]), t7 = fmaxf(sv[14], sv[15]);
        t0 = fmaxf(t0, t1); t2 = fmaxf(t2, t3); t4 = fmaxf(t4, t5); t6 = fmaxf(t6, t7);
        float tm = fmaxf(fmaxf(t0, t2), fmaxf(t4, t6));
        tm = fmaxf(tm, __shfl_xor(tm, 32, 64));

        const float mnew = fmaxf(m_run, tm);
        if (__any(tm > m_run)) {            // exact skip: corr==1 for all lanes otherwise
            const float corr = __expf(m_run - mnew);
            l_run *= corr;
#pragma unroll
            for (int e = 0; e < 4; ++e)
#pragma unroll
                for (int i = 0; i < 16; ++i) acc[e][i] *= corr;
            m_run = mnew;
        }

#pragma unroll
        for (int i = 0; i < 16; ++i) sv[i] = __expf(sv[i] - m_run);
        float r0 = (sv[0] + sv[1]) + (sv[2] + sv[3]);
        float r1 = (sv[4] + sv[5]) + (sv[6] + sv[7]);
        float r2 = (sv[8] + sv[9]) + (sv[10] + sv[11]);
        float r3 = (sv[12] + sv[13]) + (sv[14] + sv[15]);
        float rs = (r0 + r1) + (r2 + r3);
        rs += __shfl_xor(rs, 32, 64);
        l_run += rs;

        // --- P^T pack + cross-half redistribution into PV B-fragments
        unsigned u0 = __builtin_bit_cast(unsigned, __builtin_amdgcn_cvt_pkrtz(sv[0],  sv[1]));
        unsigned u1 = __builtin_bit_cast(unsigned, __builtin_amdgcn_cvt_pkrtz(sv[2],  sv[3]));
        unsigned u2 = __builtin_bit_cast(unsigned, __builtin_amdgcn_cvt_pkrtz(sv[4],  sv[5]));
        unsigned u3 = __builtin_bit_cast(unsigned, __builtin_amdgcn_cvt_pkrtz(sv[6],  sv[7]));
        unsigned u4 = __builtin_bit_cast(unsigned, __builtin_amdgcn_cvt_pkrtz(sv[8],  sv[9]));
        unsigned u5 = __builtin_bit_cast(unsigned, __builtin_amdgcn_cvt_pkrtz(sv[10], sv[11]));
        unsigned u6 = __builtin_bit_cast(unsigned, __builtin_amdgcn_cvt_pkrtz(sv[12], sv[13]));
        unsigned u7 = __builtin_bit_cast(unsigned, __builtin_amdgcn_cvt_pkrtz(sv[14], sv[15]));
        permswap(u0, u2); permswap(u1, u3);
        permswap(u4, u6); permswap(u5, u7);
        union uf8 { unsigned w[4]; f16x8 v; };
        uf8 p0; p0.w[0] = u0; p0.w[1] = u1; p0.w[2] = u2; p0.w[3] = u3;
        uf8 p1; p1.w[0] = u4; p1.w[1] = u5; p1.w[2] = u6; p1.w[3] = u7;

        // --- O^T += V^T · P^T
#pragma unroll
        for (int e = 0; e < 4; ++e) {
            acc[e] = __builtin_amdgcn_mfma_f32_32x32x16_f16(vf[2 * e],     p0.v, acc[e], 0, 0, 0);
            acc[e] = __builtin_amdgcn_mfma_f32_32x32x16_f16(vf[2 * e + 1], p1.v, acc[e], 0, 0, 0);
        }
    }

    // --- KV-split combine: B writes partial (m,l,O) to LDS; A merges + stores
    if (role) {
        if (hi == 0) { mlbuf[pairid][0][q] = m_run; mlbuf[pairid][1][q] = l_run; }
#pragma unroll
        for (int e = 0; e < 4; ++e)
#pragma unroll
            for (int i = 0; i < 16; ++i) {
                const int erow = e * 32 + (i & 3) + 8 * (i >> 2) + 4 * hi;
                obuf[pairid][q][erow] = (_Float16)acc[e][i];
            }
    }
    __syncthreads();
    if (!role) {
        const float mb = mlbuf[pairid][0][q];
        const float lb = mlbuf[pairid][1][q];
        const float ms = fmaxf(m_run, mb);
        const float ca = __expf(m_run - ms);
        const float cb = __expf(mb - ms);
        const float rinv = 1.0f / (l_run * ca + lb * cb);
        float* orow = out + (size_t)q_abs * (NHEAD * DHEAD) + h * DHEAD;
#pragma unroll
        for (int e = 0; e < 4; ++e) {
#pragma unroll
            for (int g = 0; g < 4; ++g) {
                f32x4 vv;
#pragma unroll
                for (int c = 0; c < 4; ++c) {
                    const int i = g * 4 + c;
                    const int erow = e * 32 + 8 * g + 4 * hi + c;
                    vv[c] = (acc[e][i] * ca + (float)obuf[pairid][q][erow] * cb) * rinv;
                }
                *(f32x4*)(orow + e * 32 + 8 * g + 4 * hi) = vv;
            }
        }
    }
}

// ---------------------------------------------------------------------------
extern "C" void kernel_launch(void* const* d_in, const int* in_sizes, int n_in,
                              void* d_out, int out_size, void* d_ws, size_t ws_size,
                              hipStream_t stream) {
    const float* q_in = (const float*)d_in[0];
    const float* k_in = (const float*)d_in[1];
    const float* v_in = (const float*)d_in[2];
    // d_in[3] = attention_mask (strict causal triu) -- implemented analytically
    const float* w_qk = (const float*)d_in[4];
    const float* w_v  = (const float*)d_in[5];
    float* out = (float*)d_out;

    const size_t mat_elems = (size_t)NHEAD * S_LEN * DHEAD;
    const size_t w_elems   = (size_t)NHEAD * DHEAD * DHEAD;
    _Float16* Qp   = (_Float16*)d_ws;
    _Float16* Kp   = Qp + mat_elems;
    _Float16* Vt   = Kp + mat_elems;
    _Float16* Wqkt = Vt + mat_elems;
    _Float16* Wvt  = Wqkt + w_elems;

    transpose_w_kernel<<<dim3(16, NHEAD, 2), dim3(256), 0, stream>>>(w_qk, w_v, Wqkt, Wvt);
    proj_kernel<<<dim3(NHEAD * 32), dim3(256), 0, stream>>>(q_in, k_in, v_in, Wqkt, Wvt, Qp, Kp, Vt);
    attn_kernel<<<dim3(16, NHEAD), dim3(512), 0, stream>>>(Qp, Kp, Vt, out);
}